// Round 7
// baseline (280.564 us; speedup 1.0000x reference)
//
#include <hip/hip_runtime.h>

// H2GCNConv: out[:, 0:128]   = segment_sum(w1 * x[col1], row1)
//            out[:, 128:256] = segment_sum(w2 * x[col2], row2)
// N = 50000, d = 128, out stride = 256 floats.
//
// Round 7: (1) 512-row buckets (98) — bin_scatter flush bursts ~584 B instead
// of ~73 B; (2) bucket_sort streams 2 passes and scatters 4 B records directly
// into its private 32-64 KB output window (single-XCD L2 coalesces full lines;
// round-5 showed cross-XCD windows pay 64 B/record); (3) spmm half-wave/edge:
// uint2 (4-elem) gathers, cross-half shuffle reduce, float4 NT store.

#define N_NODES 50000
#define D 128
#define OUT_STRIDE 256

#define BUCKET_SHIFT 9                      // 512 rows / bucket
#define BROWS (1 << BUCKET_SHIFT)
#define NBUCK ((N_NODES + BROWS - 1) >> BUCKET_SHIFT)   // 98
#define CHUNK 7168                          // edges per bin_scatter WG

typedef float vf4 __attribute__((ext_vector_type(4)));

static inline size_t align256(size_t x) { return (x + 255) & ~(size_t)255; }

__device__ __forceinline__ unsigned f32_to_bf16_bits(float f) {
    unsigned u = __float_as_uint(f);
    return (u + 0x7fffu + ((u >> 16) & 1u)) >> 16;   // RNE
}

// ---------------- 1. coarse histogram: rows -> 98 buckets x 2 graphs -------

__global__ void __launch_bounds__(256) coarse_hist(
        const int* __restrict__ ei1, int E1,
        const int* __restrict__ ei2, int E2,
        int* __restrict__ bcnt) {           // [2*NBUCK], pre-zeroed
    __shared__ int h[2 * NBUCK];
    for (int i = threadIdx.x; i < 2 * NBUCK; i += 256) h[i] = 0;
    __syncthreads();
    int q1 = E1 >> 2, q2 = E2 >> 2;
    long long total = q1 + q2;
    for (long long i = (long long)blockIdx.x * 256 + threadIdx.x; i < total;
         i += (long long)gridDim.x * 256) {
        if (i < q1) {
            int4 r = ((const int4*)ei1)[i];
            atomicAdd(&h[r.x >> BUCKET_SHIFT], 1);
            atomicAdd(&h[r.y >> BUCKET_SHIFT], 1);
            atomicAdd(&h[r.z >> BUCKET_SHIFT], 1);
            atomicAdd(&h[r.w >> BUCKET_SHIFT], 1);
        } else {
            int4 r = ((const int4*)ei2)[i - q1];
            atomicAdd(&h[NBUCK + (r.x >> BUCKET_SHIFT)], 1);
            atomicAdd(&h[NBUCK + (r.y >> BUCKET_SHIFT)], 1);
            atomicAdd(&h[NBUCK + (r.z >> BUCKET_SHIFT)], 1);
            atomicAdd(&h[NBUCK + (r.w >> BUCKET_SHIFT)], 1);
        }
    }
    if (blockIdx.x == 0) {   // tails if E not divisible by 4
        int t1 = E1 & 3, t2 = E2 & 3;
        int t = threadIdx.x;
        if (t < t1) atomicAdd(&h[ei1[(q1 << 2) + t] >> BUCKET_SHIFT], 1);
        else if (t - t1 < t2)
            atomicAdd(&h[NBUCK + (ei2[(q2 << 2) + (t - t1)] >> BUCKET_SHIFT)], 1);
    }
    __syncthreads();
    for (int i = threadIdx.x; i < 2 * NBUCK; i += 256)
        if (h[i]) atomicAdd(&bcnt[i], h[i]);
}

// ---------------- 2. scan bucket counts -> bases (1 workgroup) -------------

__global__ void __launch_bounds__(256) bucket_scan(
        const int* __restrict__ bcnt, int* __restrict__ bsBase,
        int* __restrict__ bsFill) {
    __shared__ int wsum[4];
    int t = threadIdx.x, lane = t & 63, wid = t >> 6;
    for (int g = 0; g < 2; ++g) {
        const int* c = bcnt + g * NBUCK;
        int i0 = 2 * t, i1 = 2 * t + 1;
        int v0 = (i0 < NBUCK) ? c[i0] : 0;
        int v1 = (i1 < NBUCK) ? c[i1] : 0;
        int p = v0 + v1, s = p;
        #pragma unroll
        for (int d = 1; d < 64; d <<= 1) { int u = __shfl_up(s, d, 64); if (lane >= d) s += u; }
        if (lane == 63) wsum[wid] = s;
        __syncthreads();
        int add = 0;
        #pragma unroll
        for (int k = 0; k < 4; ++k) if (k < wid) add += wsum[k];
        s += add;                      // inclusive over pairs
        int excl = s - p;
        if (i0 < NBUCK) { bsBase[g * NBUCK + i0] = excl;      bsFill[g * NBUCK + i0] = excl; }
        if (i1 < NBUCK) { bsBase[g * NBUCK + i1] = excl + v0; bsFill[g * NBUCK + i1] = excl + v0; }
        __syncthreads();               // wsum reuse
    }
}

// ---------------- 3. binned scatter: edges -> bucket-grouped records -------

__global__ void __launch_bounds__(256) bin_scatter(
        const int* __restrict__ ei1, const float* __restrict__ w1, int E1, int nch1,
        const int* __restrict__ ei2, const float* __restrict__ w2, int E2,
        int* __restrict__ bsFill, uint2* __restrict__ inter) {
    int g, chunk;
    if ((int)blockIdx.x < nch1) { g = 0; chunk = blockIdx.x; }
    else                        { g = 1; chunk = blockIdx.x - nch1; }
    const int*   ei = g ? ei2 : ei1;
    const float* w  = g ? w2  : w1;
    int E           = g ? E2  : E1;
    uint2* out      = inter + (g ? E1 : 0);
    int*   fill     = bsFill + g * NBUCK;
    int e0  = chunk * CHUNK;
    int cnt = min(CHUNK, E - e0);

    __shared__ uint2 stage[CHUNK];              // 56 KB
    __shared__ int cntb[NBUCK], cur[NBUCK], gbase[NBUCK];
    __shared__ int wsum[4];
    int t = threadIdx.x, lane = t & 63, wid = t >> 6;
    for (int b = t; b < NBUCK; b += 256) cntb[b] = 0;
    __syncthreads();
    // pass 1: count bins
    for (int i = t; i < cnt; i += 256)
        atomicAdd(&cntb[ei[e0 + i] >> BUCKET_SHIFT], 1);
    __syncthreads();
    // exclusive scan over 98 bins (2 elems/thread)
    {
        int i0 = 2 * t, i1 = 2 * t + 1;
        int v0 = (i0 < NBUCK) ? cntb[i0] : 0;
        int v1 = (i1 < NBUCK) ? cntb[i1] : 0;
        int p = v0 + v1, s = p;
        #pragma unroll
        for (int d = 1; d < 64; d <<= 1) { int u = __shfl_up(s, d, 64); if (lane >= d) s += u; }
        if (lane == 63) wsum[wid] = s;
        __syncthreads();
        int add = 0;
        #pragma unroll
        for (int k = 0; k < 4; ++k) if (k < wid) add += wsum[k];
        s += add;
        int excl = s - p;
        if (i0 < NBUCK) cur[i0] = excl;
        if (i1 < NBUCK) cur[i1] = excl + v0;
    }
    __syncthreads();
    // reserve global space per bin
    for (int b = t; b < NBUCK; b += 256) {
        int c = cntb[b];
        gbase[b] = c ? atomicAdd(&fill[b], c) : 0;
    }
    __syncthreads();
    // pass 2: rank + stage
    for (int i = t; i < cnt; i += 256) {
        int row = ei[e0 + i];
        int col = ei[E + e0 + i];
        unsigned rec = (unsigned)col | (f32_to_bf16_bits(w[e0 + i]) << 16);
        int b = row >> BUCKET_SHIFT;
        int pos = atomicAdd(&cur[b], 1);
        stage[pos] = make_uint2((unsigned)(row & (BROWS - 1)), rec);
    }
    __syncthreads();
    // flush each bin as a contiguous burst (wave per bin, round-robin)
    for (int b = wid; b < NBUCK; b += 4) {
        int c = cntb[b];
        if (!c) continue;
        int s0 = cur[b] - c;         // cur[b] is now end-of-bin in stage
        int gb = gbase[b];
        for (int i = lane; i < c; i += 64)
            out[gb + i] = stage[s0 + i];
    }
}

// ---------------- 4. per-bucket counting sort (streaming) ------------------
// Direct global scatter: each WG's output window is <= 64 KB and lives in one
// XCD's L2, so random 4 B stores coalesce into full lines before writeback.

__global__ void __launch_bounds__(256) bucket_sort(
        const int* __restrict__ bsBase, const int* __restrict__ bsFill,
        const uint2* __restrict__ inter, unsigned* __restrict__ colw,
        int* __restrict__ off1, int* __restrict__ off2, int E1) {
    int b = blockIdx.x, g = blockIdx.y;
    int base = bsBase[g * NBUCK + b];
    int cnt  = bsFill[g * NBUCK + b] - base;
    const uint2* src = inter + (g ? E1 : 0) + base;
    unsigned*    dst = colw  + (g ? E1 : 0) + base;
    int*         off = g ? off2 : off1;

    __shared__ int crow[BROWS], cur[BROWS];   // 4 KB
    __shared__ int wsum[4];
    int t = threadIdx.x, lane = t & 63, wid = t >> 6;
    crow[2 * t] = 0; crow[2 * t + 1] = 0;
    __syncthreads();
    // pass 1: count rows (coalesced read)
    for (int i = t; i < cnt; i += 256)
        atomicAdd(&crow[src[i].x], 1);
    __syncthreads();
    // scan 512 counts (2/thread); write off ends + cur starts
    {
        int i0 = 2 * t, i1 = 2 * t + 1;
        int v0 = crow[i0], v1 = crow[i1];
        int p = v0 + v1, s = p;
        #pragma unroll
        for (int d = 1; d < 64; d <<= 1) { int u = __shfl_up(s, d, 64); if (lane >= d) s += u; }
        if (lane == 63) wsum[wid] = s;
        __syncthreads();
        int add = 0;
        #pragma unroll
        for (int k = 0; k < 4; ++k) if (k < wid) add += wsum[k];
        s += add;                       // inclusive over pairs
        cur[i0] = s - p;                // exclusive start of i0
        cur[i1] = s - v1;               // exclusive start of i1
        int grow0 = (b << BUCKET_SHIFT) + i0;
        int grow1 = grow0 + 1;
        if (grow0 < N_NODES) off[grow0] = base + (s - v1);   // end of row i0
        if (grow1 < N_NODES) off[grow1] = base + s;          // end of row i1
    }
    __syncthreads();
    // pass 2: re-read + direct scatter into the bucket's output window
    for (int i = t; i < cnt; i += 256) {
        uint2 v = src[i];
        int pos = atomicAdd(&cur[v.x], 1);
        dst[pos] = v.y;
    }
}

// ---------------- 5. x -> bf16x2 pack --------------------------------------

__global__ void cvt_bf16(const float* __restrict__ x, uint2* __restrict__ xb4, int n4) {
    int i = blockIdx.x * blockDim.x + threadIdx.x;
    if (i >= n4) return;
    float4 v = ((const float4*)x)[i];
    unsigned a = f32_to_bf16_bits(v.x);
    unsigned b = f32_to_bf16_bits(v.y);
    unsigned c = f32_to_bf16_bits(v.z);
    unsigned d = f32_to_bf16_bits(v.w);
    xb4[i] = make_uint2(a | (b << 16), c | (d << 16));
}

// ---------------- 6. SpMM: half-wave per edge, uint2 gathers ---------------
// Lanes 0-31 process even edges of the segment, lanes 32-63 odd edges; each
// lane gathers 4 elements (uint2). Cross-half shuffle-add, float4 NT store.

__global__ void __launch_bounds__(256) spmm_bf16(
        const uint2* __restrict__ xb2,  // [N,32] uint2 = 4 bf16 each
        const int* __restrict__ off1, const unsigned* __restrict__ colw1,
        const int* __restrict__ off2, const unsigned* __restrict__ colw2,
        float* __restrict__ out) {
    int seg  = (int)((blockIdx.x * blockDim.x + threadIdx.x) >> 6);
    int lane = threadIdx.x & 63;
    int half = lane >> 5;
    int hl   = lane & 31;
    if (seg >= 2 * N_NODES) return;
    int g    = (seg >= N_NODES) ? 1 : 0;
    int row  = g ? seg - N_NODES : seg;
    const int*      off  = g ? off2  : off1;
    const unsigned* colw = g ? colw2 : colw1;
    int s = row ? off[row - 1] : 0;
    int e = off[row];

    float ax = 0.f, ay = 0.f, az = 0.f, aw = 0.f;
    int j = s + half;
    for (; j + 2 < e; j += 4) {       // 4 edges per wave-iteration
        unsigned c0 = colw[j];
        unsigned c1 = colw[j + 2];
        uint2 p0 = xb2[(size_t)(c0 & 0xffffu) * 32 + hl];
        uint2 p1 = xb2[(size_t)(c1 & 0xffffu) * 32 + hl];
        float w0 = __int_as_float((int)(c0 & 0xffff0000u));
        float w1 = __int_as_float((int)(c1 & 0xffff0000u));
        ax += w0 * __int_as_float((int)(p0.x << 16));
        ay += w0 * __int_as_float((int)(p0.x & 0xffff0000u));
        az += w0 * __int_as_float((int)(p0.y << 16));
        aw += w0 * __int_as_float((int)(p0.y & 0xffff0000u));
        ax += w1 * __int_as_float((int)(p1.x << 16));
        ay += w1 * __int_as_float((int)(p1.x & 0xffff0000u));
        az += w1 * __int_as_float((int)(p1.y << 16));
        aw += w1 * __int_as_float((int)(p1.y & 0xffff0000u));
    }
    for (; j < e; j += 2) {
        unsigned c = colw[j];
        uint2 p = xb2[(size_t)(c & 0xffffu) * 32 + hl];
        float w = __int_as_float((int)(c & 0xffff0000u));
        ax += w * __int_as_float((int)(p.x << 16));
        ay += w * __int_as_float((int)(p.x & 0xffff0000u));
        az += w * __int_as_float((int)(p.y << 16));
        aw += w * __int_as_float((int)(p.y & 0xffff0000u));
    }
    // cross-half reduction (lane ^ 32)
    ax += __shfl_xor(ax, 32, 64);
    ay += __shfl_xor(ay, 32, 64);
    az += __shfl_xor(az, 32, 64);
    aw += __shfl_xor(aw, 32, 64);
    if (half == 0) {
        vf4 r; r.x = ax; r.y = ay; r.z = az; r.w = aw;
        vf4* o = (vf4*)(out + (size_t)row * OUT_STRIDE + g * D);
        __builtin_nontemporal_store(r, o + hl);
    }
}

// ---------------- atomic scatter (fallback if ws too small) ----------------

__global__ void spmm_scatter(const float* __restrict__ x,
                             const int* __restrict__ ei,
                             const float* __restrict__ w,
                             float* __restrict__ out,
                             int E, int col_off) {
    long long gid = (long long)blockIdx.x * blockDim.x + threadIdx.x;
    int e    = (int)(gid >> 5);
    int lane = (int)(gid & 31);
    if (e >= E) return;
    int row  = ei[e];
    int col  = ei[E + e];
    float wv = w[e];
    const float4* xv = (const float4*)(x + (size_t)col * D);
    float4 v = xv[lane];
    float* o = out + (size_t)row * OUT_STRIDE + col_off + lane * 4;
    atomicAdd(o + 0, wv * v.x);
    atomicAdd(o + 1, wv * v.y);
    atomicAdd(o + 2, wv * v.z);
    atomicAdd(o + 3, wv * v.w);
}

extern "C" void kernel_launch(void* const* d_in, const int* in_sizes, int n_in,
                              void* d_out, int out_size, void* d_ws, size_t ws_size,
                              hipStream_t stream) {
    const float* x   = (const float*)d_in[0];
    const int*   ei1 = (const int*)d_in[1];
    const float* w1  = (const float*)d_in[2];
    const int*   ei2 = (const int*)d_in[3];
    const float* w2  = (const float*)d_in[4];
    float* out = (float*)d_out;

    const int E1 = in_sizes[1] / 2;   // 800000
    const int E2 = in_sizes[3] / 2;   // 1600000
    const int block = 256;

    // Workspace: bcnt | bsBase | bsFill | off1 | off2 | inter | colw | xb
    size_t buck_b = align256((size_t)2 * NBUCK * sizeof(int));
    size_t off_b  = align256((size_t)N_NODES * sizeof(int));
    size_t o_bcnt = 0;
    size_t o_base = o_bcnt + buck_b;
    size_t o_fill = o_base + buck_b;
    size_t o_off1 = o_fill + buck_b;
    size_t o_off2 = o_off1 + off_b;
    size_t o_int  = o_off2 + off_b;
    size_t o_colw = o_int + align256((size_t)(E1 + E2) * sizeof(uint2));
    size_t o_xb   = o_colw + align256((size_t)(E1 + E2) * sizeof(unsigned));
    size_t needed = o_xb + align256((size_t)N_NODES * 64 * sizeof(unsigned));

    if (ws_size < needed) {
        // Fallback: atomic scatter (round-0).
        (void)hipMemsetAsync(d_out, 0, (size_t)out_size * sizeof(float), stream);
        long long th1 = (long long)E1 * 32;
        spmm_scatter<<<(int)((th1 + block - 1) / block), block, 0, stream>>>(
            x, ei1, w1, out, E1, 0);
        long long th2 = (long long)E2 * 32;
        spmm_scatter<<<(int)((th2 + block - 1) / block), block, 0, stream>>>(
            x, ei2, w2, out, E2, D);
        return;
    }

    char* ws = (char*)d_ws;
    int*      bcnt   = (int*)(ws + o_bcnt);
    int*      bsBase = (int*)(ws + o_base);
    int*      bsFill = (int*)(ws + o_fill);
    int*      off1   = (int*)(ws + o_off1);
    int*      off2   = (int*)(ws + o_off2);
    uint2*    inter  = (uint2*)(ws + o_int);
    unsigned* colw   = (unsigned*)(ws + o_colw);
    unsigned* xb     = (unsigned*)(ws + o_xb);

    // 1. zero bucket counters
    (void)hipMemsetAsync(bcnt, 0, (size_t)2 * NBUCK * sizeof(int), stream);

    // 2. coarse histogram (LDS-aggregated)
    coarse_hist<<<512, block, 0, stream>>>(ei1, E1, ei2, E2, bcnt);

    // 3. bucket bases (1 WG)
    bucket_scan<<<1, block, 0, stream>>>(bcnt, bsBase, bsFill);

    // 4. binned scatter into bucket-grouped intermediate
    {
        int nch1 = (E1 + CHUNK - 1) / CHUNK;
        int nch2 = (E2 + CHUNK - 1) / CHUNK;
        bin_scatter<<<nch1 + nch2, block, 0, stream>>>(
            ei1, w1, E1, nch1, ei2, w2, E2, bsFill, inter);
    }

    // 5. per-bucket streaming counting sort -> final colw + off
    {
        dim3 g(NBUCK, 2);
        bucket_sort<<<g, block, 0, stream>>>(bsBase, bsFill, inter, colw,
                                             off1, off2, E1);
    }

    // 6. pack x to bf16x2
    {
        int n4 = N_NODES * 32;
        cvt_bf16<<<(n4 + block - 1) / block, block, 0, stream>>>(
            x, (uint2*)xb, n4);
    }

    // 7. gather SpMM: one wave per (row, graph)
    {
        long long threads = (long long)2 * N_NODES * 64;
        int grid = (int)((threads + block - 1) / block);
        spmm_bf16<<<grid, block, 0, stream>>>((const uint2*)xb, off1, colw,
                                              off2, colw + E1, out);
    }
}